// Round 4
// baseline (1314.715 us; speedup 1.0000x reference)
//
#include <hip/hip_runtime.h>

#define BB 4
#define SS 2048
#define DD 256
#define HH 8

typedef unsigned short u16;
typedef __attribute__((ext_vector_type(8))) short bf16x8;
typedef __attribute__((ext_vector_type(4))) float f32x4;

__device__ __forceinline__ f32x4 MFMA(bf16x8 a, bf16x8 b, f32x4 c) {
    return __builtin_amdgcn_mfma_f32_16x16x32_bf16(a, b, c, 0, 0, 0);
}

__device__ __forceinline__ u16 f2bf_rtn(float x) {
    unsigned u = __float_as_uint(x);
    u += 0x7FFFu + ((u >> 16) & 1u);
    return (u16)(u >> 16);
}
__device__ __forceinline__ float bf2f(u16 h) {
    return __uint_as_float(((unsigned)h) << 16);
}
__device__ __forceinline__ void split2(float x, u16 &hi, u16 &lo) {
    hi = f2bf_rtn(x);
    lo = f2bf_rtn(x - bf2f(hi));
}

// ---------------- weight prep: transpose + hi/lo split ----------------
__global__ void prep_w(const float* __restrict__ W, u16* __restrict__ Whi,
                       u16* __restrict__ Wlo) {
    int n = blockIdx.x;            // 0..2047
    int h = n >> 8, e = n & 255;
    int d = threadIdx.x;           // 0..255
    float x = W[((size_t)h * 256 + d) * 256 + e];
    u16 hi, lo; split2(x, hi, lo);
    Whi[(size_t)n * 256 + d] = hi;
    Wlo[(size_t)n * 256 + d] = lo;
}

__global__ void prep_wo(const float* __restrict__ W, u16* __restrict__ Whi,
                        u16* __restrict__ Wlo) {
    int n = blockIdx.x;            // 0..255
    for (int k = threadIdx.x; k < 2048; k += 256) {
        float x = W[(size_t)k * 256 + n];
        u16 hi, lo; split2(x, hi, lo);
        Whi[(size_t)n * 2048 + k] = hi;
        Wlo[(size_t)n * 2048 + k] = lo;
    }
}

// ---------------- split-bf16 GEMM: C = A * B^T(stored [N][K]) + bias ----------------
// MODE 0: bf16-hi output -> Q/K layout [b][h][s][d]
// MODE 1: bf16-hi output -> V^T layout [b][h][d][s]
// MODE 2: fp32 output    -> C[row*N + col]
template<int MODE, bool AFP32, int TERMS, int BN>
__global__ __launch_bounds__(512, 2) void gemm_split(
    const float* __restrict__ Af,
    const u16* __restrict__ Ahi, const u16* __restrict__ Alo,
    const u16* __restrict__ Bhi, const u16* __restrict__ Blo,
    const float* __restrict__ bias,
    u16* __restrict__ Ohi,
    float* __restrict__ Of,
    int M, int N, int K, float scale)
{
    constexpr int WN = (BN == 128) ? 4 : 2;        // waves along n
    constexpr int WM = 8 / WN;                     // waves along m
    constexpr int MSUB = (128 / WM) / 16;
    constexpr int NSUB = (BN / WN) / 16;

    __shared__ u16 lA_hi[128][40], lA_lo[128][40];
    __shared__ u16 lB_hi[128][40], lB_lo[128][40];

    const int tid = threadIdx.x;
    const int lane = tid & 63, wave = tid >> 6;
    const int wm = wave / WN, wn = wave % WN;
    const int m0 = blockIdx.y * 128, n0 = blockIdx.x * BN;

    f32x4 acc[MSUB][NSUB];
#pragma unroll
    for (int i = 0; i < MSUB; ++i)
#pragma unroll
        for (int j = 0; j < NSUB; ++j) acc[i][j] = {0.f, 0.f, 0.f, 0.f};

    const int srow = tid >> 2;
    const int schunk = (tid & 3) * 8;

    for (int k0 = 0; k0 < K; k0 += 32) {
        __syncthreads();
        if (AFP32) {
            const float* g = Af + (size_t)(m0 + srow) * K + k0 + schunk;
            f32x4 a0 = *(const f32x4*)g;
            f32x4 a1 = *(const f32x4*)(g + 4);
            bf16x8 hv;
#pragma unroll
            for (int j = 0; j < 4; ++j) hv[j] = (short)f2bf_rtn(a0[j]);
#pragma unroll
            for (int j = 0; j < 4; ++j) hv[4 + j] = (short)f2bf_rtn(a1[j]);
            *(bf16x8*)&lA_hi[srow][schunk] = hv;
        } else {
            size_t ga = (size_t)(m0 + srow) * K + k0 + schunk;
            *(bf16x8*)&lA_hi[srow][schunk] = *(const bf16x8*)(Ahi + ga);
            if (TERMS == 3)
                *(bf16x8*)&lA_lo[srow][schunk] = *(const bf16x8*)(Alo + ga);
        }
        if (BN == 128 || tid < BN * 4) {
            size_t gb = (size_t)(n0 + srow) * K + k0 + schunk;
            *(bf16x8*)&lB_hi[srow][schunk] = *(const bf16x8*)(Bhi + gb);
            if (TERMS >= 2)
                *(bf16x8*)&lB_lo[srow][schunk] = *(const bf16x8*)(Blo + gb);
        }
        __syncthreads();

        const int kf = (lane >> 4) * 8;
        const int rA = wm * (128 / WM), rB = wn * (BN / WN);
        bf16x8 bh[NSUB], bl[NSUB];
#pragma unroll
        for (int ns = 0; ns < NSUB; ++ns) {
            bh[ns] = *(bf16x8*)&lB_hi[rB + ns * 16 + (lane & 15)][kf];
            if (TERMS >= 2)
                bl[ns] = *(bf16x8*)&lB_lo[rB + ns * 16 + (lane & 15)][kf];
        }
#pragma unroll
        for (int ms = 0; ms < MSUB; ++ms) {
            bf16x8 ah = *(bf16x8*)&lA_hi[rA + ms * 16 + (lane & 15)][kf];
            bf16x8 al;
            if (TERMS == 3) al = *(bf16x8*)&lA_lo[rA + ms * 16 + (lane & 15)][kf];
#pragma unroll
            for (int ns = 0; ns < NSUB; ++ns) {
                acc[ms][ns] = MFMA(ah, bh[ns], acc[ms][ns]);
                if (TERMS == 3) acc[ms][ns] = MFMA(al, bh[ns], acc[ms][ns]);
                if (TERMS >= 2) acc[ms][ns] = MFMA(ah, bl[ns], acc[ms][ns]);
            }
        }
    }

#pragma unroll
    for (int ms = 0; ms < MSUB; ++ms)
#pragma unroll
        for (int ns = 0; ns < NSUB; ++ns)
#pragma unroll
            for (int r = 0; r < 4; ++r) {
                int row = m0 + wm * (128 / WM) + ms * 16 + (lane >> 4) * 4 + r;
                int col = n0 + wn * (BN / WN) + ns * 16 + (lane & 15);
                float v = (acc[ms][ns][r] + bias[col]) * scale;
                if (MODE == 2) {
                    Of[(size_t)row * N + col] = v;
                } else {
                    int b = row >> 11, s = row & 2047, hh = col >> 8, e = col & 255;
                    size_t idx;
                    if (MODE == 0)
                        idx = ((size_t)(b * HH + hh) * SS + s) * DD + e;
                    else
                        idx = ((size_t)(b * HH + hh) * DD + e) * SS + s;
                    Ohi[idx] = f2bf_rtn(v);
                }
            }
}

// ---------------- flash attention: no LDS, operands direct from global via L1 ----------------
// Swapped QK^T (S^T = MFMA(K_frag, Q_frag)): q = lane&15 is lane-local, softmax
// needs only 2 shuffles. K-frag rows use pi_t(l) = 8*(l>>2)+(l&3) + {0,4,32,36}[t]
// so exp'd S^T registers ARE the PV B-operand fragments. K/V fragment addresses
// are IDENTICAL across the 8 waves of a block -> L1 serves 7/8 of reads; no
// __syncthreads anywhere (raw s_barrier keeps waves loosely in step, no vmcnt drain).
__global__ __launch_bounds__(512, 3) void attn_kernel(
    const u16* __restrict__ Qhi,
    const u16* __restrict__ Khi,
    const u16* __restrict__ Vhi,
    u16* __restrict__ Rhi, u16* __restrict__ Rlo)
{
    const int lane = threadIdx.x & 63, wave = threadIdx.x >> 6;
    const int m = lane & 15, g = lane >> 4;
    const int bh = blockIdx.y;                     // 0..31 (b*8+h)
    const size_t base = (size_t)bh * SS * DD;
    const int q0 = blockIdx.x * 128 + wave * 16;

    // Q fragments (B-operand: col=q=m, d-chunk = g*8 within ks*32)
    bf16x8 qh[8];
#pragma unroll
    for (int ks = 0; ks < 8; ++ks)
        qh[ks] = *(const bf16x8*)(Qhi + base + (size_t)(q0 + m) * DD + ks * 32 + g * 8);

    // K row bases for the pi permutation (t in 0..3 -> row offsets {0,4,32,36})
    const int r0 = ((m >> 2) << 3) + (m & 3);
    const u16* kptr[4];
#pragma unroll
    for (int t = 0; t < 4; ++t) {
        const int dT = (t & 1) * 4 + (t >> 1) * 32;
        kptr[t] = Khi + base + (size_t)(r0 + dT) * DD + g * 8;
    }
    // V^T base: lane reads rows m + 16*e16, cols kv + c*32 + g*8
    const u16* vptr = Vhi + base + (size_t)m * SS + g * 8;

    float m2 = -1e30f, l = 0.f;
    f32x4 acc[16];
#pragma unroll
    for (int e = 0; e < 16; ++e) acc[e] = {0.f, 0.f, 0.f, 0.f};

    for (int kv = 0; kv < SS; kv += 64) {
        const size_t kvo = (size_t)kv * DD;

        // QK^T (swapped): s[t] holds keys pi_t(4g+r) for q=m
        f32x4 s[4];
#pragma unroll
        for (int t = 0; t < 4; ++t) s[t] = {0.f, 0.f, 0.f, 0.f};
#pragma unroll
        for (int ks = 0; ks < 8; ++ks)
#pragma unroll
            for (int t = 0; t < 4; ++t) {
                bf16x8 kf_ = *(const bf16x8*)(kptr[t] + kvo + ks * 32);
                s[t] = MFMA(kf_, qh[ks], s[t]);
            }

        // online softmax in log2 domain (16 in-lane key-values share q=m)
        f32x4 vm;
#pragma unroll
        for (int r = 0; r < 4; ++r)
            vm[r] = fmaxf(fmaxf(s[0][r], s[1][r]), fmaxf(s[2][r], s[3][r]));
        float mx = fmaxf(fmaxf(vm[0], vm[1]), fmaxf(vm[2], vm[3]));
        mx = fmaxf(mx, __shfl_xor(mx, 16));
        mx = fmaxf(mx, __shfl_xor(mx, 32));

        if (__ballot(mx > m2 + 11.0f)) {           // defer-rescale (T13)
            float mn = fmaxf(m2, mx);
            float f = __builtin_amdgcn_exp2f(m2 - mn);
            m2 = mn;
            l *= f;
#pragma unroll
            for (int e = 0; e < 16; ++e) acc[e] *= f;
        }
#pragma unroll
        for (int t = 0; t < 4; ++t)
#pragma unroll
            for (int r = 0; r < 4; ++r)
                s[t][r] = __builtin_amdgcn_exp2f(s[t][r] - m2);

        f32x4 vs = (s[0] + s[1]) + (s[2] + s[3]);
        float sum = (vs[0] + vs[1]) + (vs[2] + vs[3]);
        sum += __shfl_xor(sum, 16);
        sum += __shfl_xor(sum, 32);
        l += sum;

        // PV: O^T[e][q] += V^T[e][k] * P^T[k][q]; P frags in-register
#pragma unroll
        for (int c = 0; c < 2; ++c) {
            bf16x8 pb;
#pragma unroll
            for (int j = 0; j < 4; ++j) pb[j] = (short)f2bf_rtn(s[2 * c][j]);
#pragma unroll
            for (int j = 0; j < 4; ++j) pb[4 + j] = (short)f2bf_rtn(s[2 * c + 1][j]);
#pragma unroll
            for (int e = 0; e < 16; ++e) {
                bf16x8 vf = *(const bf16x8*)(vptr + (size_t)e * (16 * SS) + kv + c * 32);
                acc[e] = MFMA(vf, pb, acc[e]);
            }
        }

        __builtin_amdgcn_s_barrier();              // cohesion only; no LDS hazard
    }

    // epilogue: lane owns q=m; e = e16*16 + 4g + r
    const int b = bh >> 3, h = bh & 7;
    float inv = 1.0f / l;
    const size_t rowbase = ((size_t)(b * SS + q0 + m)) * (DD * HH) + h;
#pragma unroll
    for (int e16 = 0; e16 < 16; ++e16)
#pragma unroll
        for (int r = 0; r < 4; ++r) {
            int e = e16 * 16 + g * 4 + r;
            float v = acc[e16][r] * inv;
            u16 hh2, ll2; split2(v, hh2, ll2);
            Rhi[rowbase + (size_t)e * HH] = hh2;
            Rlo[rowbase + (size_t)e * HH] = ll2;
        }
}

// ---------------- launcher ----------------
extern "C" void kernel_launch(void* const* d_in, const int* in_sizes, int n_in,
                              void* d_out, int out_size, void* d_ws, size_t ws_size,
                              hipStream_t stream)
{
    (void)in_sizes; (void)n_in; (void)out_size; (void)ws_size;
    const float* k_in = (const float*)d_in[0];
    const float* v_in = (const float*)d_in[1];
    const float* q_in = (const float*)d_in[2];
    const float* Wk   = (const float*)d_in[3];
    const float* bk   = (const float*)d_in[4];
    const float* Wv   = (const float*)d_in[5];
    const float* bv   = (const float*)d_in[6];
    const float* Wq   = (const float*)d_in[7];
    const float* bq   = (const float*)d_in[8];
    const float* Wo   = (const float*)d_in[9];
    const float* bo   = (const float*)d_in[10];
    float* out = (float*)d_out;

    // workspace: 8 MB weights + 5 bf16 planes (32 MB each) = 168 MB total
    char* p = (char*)d_ws;
    const size_t MB = 1024 * 1024;
    u16* WqH = (u16*)(p + 0 * MB);
    u16* WqL = (u16*)(p + 1 * MB);
    u16* WkH = (u16*)(p + 2 * MB);
    u16* WkL = (u16*)(p + 3 * MB);
    u16* WvH = (u16*)(p + 4 * MB);
    u16* WvL = (u16*)(p + 5 * MB);
    u16* WoH = (u16*)(p + 6 * MB);
    u16* WoL = (u16*)(p + 7 * MB);
    const size_t PB = 32 * MB;
    u16* QH  = (u16*)(p + 8 * MB);
    u16* KH  = (u16*)(p + 8 * MB + 1 * PB);
    u16* VTH = (u16*)(p + 8 * MB + 2 * PB);
    u16* RH  = (u16*)(p + 8 * MB + 3 * PB);
    u16* RL  = (u16*)(p + 8 * MB + 4 * PB);

    prep_w<<<dim3(2048), dim3(256), 0, stream>>>(Wq, WqH, WqL);
    prep_w<<<dim3(2048), dim3(256), 0, stream>>>(Wk, WkH, WkL);
    prep_w<<<dim3(2048), dim3(256), 0, stream>>>(Wv, WvH, WvL);
    prep_wo<<<dim3(256), dim3(256), 0, stream>>>(Wo, WoH, WoL);

    // projections: M=8192, N=2048, K=256.
    // Q scaled by log2(e)/sqrt(D) = log2(e)/16 -> logits directly in log2 domain.
    const float qscale = 1.4426950408889634f / 16.0f;
    gemm_split<0, true, 1, 128><<<dim3(16, 64), dim3(512), 0, stream>>>(
        q_in, nullptr, nullptr, WqH, WqL, bq, QH, nullptr, 8192, 2048, 256, qscale);
    gemm_split<0, true, 1, 128><<<dim3(16, 64), dim3(512), 0, stream>>>(
        k_in, nullptr, nullptr, WkH, WkL, bk, KH, nullptr, 8192, 2048, 256, 1.0f);
    gemm_split<1, true, 2, 128><<<dim3(16, 64), dim3(512), 0, stream>>>(
        v_in, nullptr, nullptr, WvH, WvL, bv, VTH, nullptr, 8192, 2048, 256, 1.0f);

    // flash attention: 16 q-tiles x 32 (b,h)
    attn_kernel<<<dim3(16, 32), dim3(512), 0, stream>>>(
        QH, KH, VTH, RH, RL);

    // output projection: M=8192, N=256, K=2048; 128x64 tiles -> 256 blocks
    gemm_split<2, false, 3, 64><<<dim3(4, 64), dim3(512), 0, stream>>>(
        nullptr, RH, RL, WoH, WoL, bo, nullptr, out, 8192, 256, 2048, 1.0f);
}

// Round 5
// 486.542 us; speedup vs baseline: 2.7022x; 2.7022x over previous
//
#include <hip/hip_runtime.h>

#define BB 4
#define SS 2048
#define DD 256
#define HH 8

typedef unsigned short u16;
typedef __attribute__((ext_vector_type(8))) short bf16x8;
typedef __attribute__((ext_vector_type(4))) float f32x4;

__device__ __forceinline__ f32x4 MFMA(bf16x8 a, bf16x8 b, f32x4 c) {
    return __builtin_amdgcn_mfma_f32_16x16x32_bf16(a, b, c, 0, 0, 0);
}

__device__ __forceinline__ u16 f2bf_rtn(float x) {
    unsigned u = __float_as_uint(x);
    u += 0x7FFFu + ((u >> 16) & 1u);
    return (u16)(u >> 16);
}
__device__ __forceinline__ float bf2f(u16 h) {
    return __uint_as_float(((unsigned)h) << 16);
}
__device__ __forceinline__ void split2(float x, u16 &hi, u16 &lo) {
    hi = f2bf_rtn(x);
    lo = f2bf_rtn(x - bf2f(hi));
}

// ---------------- weight prep: transpose + hi/lo split ----------------
__global__ void prep_w(const float* __restrict__ W, u16* __restrict__ Whi,
                       u16* __restrict__ Wlo) {
    int n = blockIdx.x;            // 0..2047
    int h = n >> 8, e = n & 255;
    int d = threadIdx.x;           // 0..255
    float x = W[((size_t)h * 256 + d) * 256 + e];
    u16 hi, lo; split2(x, hi, lo);
    Whi[(size_t)n * 256 + d] = hi;
    Wlo[(size_t)n * 256 + d] = lo;
}

__global__ void prep_wo(const float* __restrict__ W, u16* __restrict__ Whi,
                        u16* __restrict__ Wlo) {
    int n = blockIdx.x;            // 0..255
    for (int k = threadIdx.x; k < 2048; k += 256) {
        float x = W[(size_t)k * 256 + n];
        u16 hi, lo; split2(x, hi, lo);
        Whi[(size_t)n * 2048 + k] = hi;
        Wlo[(size_t)n * 2048 + k] = lo;
    }
}

// ---------------- split-bf16 GEMM: C = A * B^T(stored [N][K]) + bias ----------------
template<int MODE, bool AFP32, int TERMS, int BN>
__global__ __launch_bounds__(512, 2) void gemm_split(
    const float* __restrict__ Af,
    const u16* __restrict__ Ahi, const u16* __restrict__ Alo,
    const u16* __restrict__ Bhi, const u16* __restrict__ Blo,
    const float* __restrict__ bias,
    u16* __restrict__ Ohi,
    float* __restrict__ Of,
    int M, int N, int K, float scale)
{
    constexpr int WN = (BN == 128) ? 4 : 2;
    constexpr int WM = 8 / WN;
    constexpr int MSUB = (128 / WM) / 16;
    constexpr int NSUB = (BN / WN) / 16;

    __shared__ u16 lA_hi[128][40], lA_lo[128][40];
    __shared__ u16 lB_hi[128][40], lB_lo[128][40];

    const int tid = threadIdx.x;
    const int lane = tid & 63, wave = tid >> 6;
    const int wm = wave / WN, wn = wave % WN;
    const int m0 = blockIdx.y * 128, n0 = blockIdx.x * BN;

    f32x4 acc[MSUB][NSUB];
#pragma unroll
    for (int i = 0; i < MSUB; ++i)
#pragma unroll
        for (int j = 0; j < NSUB; ++j) acc[i][j] = {0.f, 0.f, 0.f, 0.f};

    const int srow = tid >> 2;
    const int schunk = (tid & 3) * 8;

    for (int k0 = 0; k0 < K; k0 += 32) {
        __syncthreads();
        if (AFP32) {
            const float* g = Af + (size_t)(m0 + srow) * K + k0 + schunk;
            f32x4 a0 = *(const f32x4*)g;
            f32x4 a1 = *(const f32x4*)(g + 4);
            bf16x8 hv;
#pragma unroll
            for (int j = 0; j < 4; ++j) hv[j] = (short)f2bf_rtn(a0[j]);
#pragma unroll
            for (int j = 0; j < 4; ++j) hv[4 + j] = (short)f2bf_rtn(a1[j]);
            *(bf16x8*)&lA_hi[srow][schunk] = hv;
        } else {
            size_t ga = (size_t)(m0 + srow) * K + k0 + schunk;
            *(bf16x8*)&lA_hi[srow][schunk] = *(const bf16x8*)(Ahi + ga);
            if (TERMS == 3)
                *(bf16x8*)&lA_lo[srow][schunk] = *(const bf16x8*)(Alo + ga);
        }
        if (BN == 128 || tid < BN * 4) {
            size_t gb = (size_t)(n0 + srow) * K + k0 + schunk;
            *(bf16x8*)&lB_hi[srow][schunk] = *(const bf16x8*)(Bhi + gb);
            if (TERMS >= 2)
                *(bf16x8*)&lB_lo[srow][schunk] = *(const bf16x8*)(Blo + gb);
        }
        __syncthreads();

        const int kf = (lane >> 4) * 8;
        const int rA = wm * (128 / WM), rB = wn * (BN / WN);
        bf16x8 bh[NSUB], bl[NSUB];
#pragma unroll
        for (int ns = 0; ns < NSUB; ++ns) {
            bh[ns] = *(bf16x8*)&lB_hi[rB + ns * 16 + (lane & 15)][kf];
            if (TERMS >= 2)
                bl[ns] = *(bf16x8*)&lB_lo[rB + ns * 16 + (lane & 15)][kf];
        }
#pragma unroll
        for (int ms = 0; ms < MSUB; ++ms) {
            bf16x8 ah = *(bf16x8*)&lA_hi[rA + ms * 16 + (lane & 15)][kf];
            bf16x8 al;
            if (TERMS == 3) al = *(bf16x8*)&lA_lo[rA + ms * 16 + (lane & 15)][kf];
#pragma unroll
            for (int ns = 0; ns < NSUB; ++ns) {
                acc[ms][ns] = MFMA(ah, bh[ns], acc[ms][ns]);
                if (TERMS == 3) acc[ms][ns] = MFMA(al, bh[ns], acc[ms][ns]);
                if (TERMS >= 2) acc[ms][ns] = MFMA(ah, bl[ns], acc[ms][ns]);
            }
        }
    }

#pragma unroll
    for (int ms = 0; ms < MSUB; ++ms)
#pragma unroll
        for (int ns = 0; ns < NSUB; ++ns)
#pragma unroll
            for (int r = 0; r < 4; ++r) {
                int row = m0 + wm * (128 / WM) + ms * 16 + (lane >> 4) * 4 + r;
                int col = n0 + wn * (BN / WN) + ns * 16 + (lane & 15);
                float v = (acc[ms][ns][r] + bias[col]) * scale;
                if (MODE == 2) {
                    Of[(size_t)row * N + col] = v;
                } else {
                    int b = row >> 11, s = row & 2047, hh = col >> 8, e = col & 255;
                    size_t idx;
                    if (MODE == 0)
                        idx = ((size_t)(b * HH + hh) * SS + s) * DD + e;
                    else
                        idx = ((size_t)(b * HH + hh) * DD + e) * SS + s;
                    Ohi[idx] = f2bf_rtn(v);
                }
            }
}

// ---------------- flash attention: 32q/wave, double-buffered LDS pipeline ----------------
// Swapped QK^T; pi_t(l)=8*(l>>2)+(l&3)+4t covers keys 0..31 for t in {0,1}; the exp'd
// S^T registers ARE the PV B-fragments. K LDS [32][264] with per-row XOR column swizzle
// fK(r)=(r&4)^((r&3)<<1)^((r>>3)&3) -> reads spread exactly 8 lanes per 16B bank-slot.
// V LDS [256][40] (80B rows) -> slot=(5m+g)&7, uniform. One __syncthreads per tile;
// global loads for t+1 issue before compute(t) and land in regs under the MFMA phase.
__global__ __launch_bounds__(512, 2) void attn_kernel(
    const u16* __restrict__ Qhi,
    const u16* __restrict__ Khi,
    const u16* __restrict__ Vhi,
    u16* __restrict__ Rhi, u16* __restrict__ Rlo)
{
    __shared__ u16 lK[2][32][264];
    __shared__ u16 lV[2][256][40];

    const int tid = threadIdx.x, lane = tid & 63, wave = tid >> 6;
    const int m = lane & 15, g = lane >> 4;
    const int bh = blockIdx.y;                     // 0..31 (b*8+h)
    const size_t base = (size_t)bh * SS * DD;
    const int q0 = blockIdx.x * 256 + wave * 32;

    // Q fragments, 2 q-groups of 16 (B-operand: col=q=m, d-chunk g*8 within ks*32)
    bf16x8 qh[2][8];
#pragma unroll
    for (int qg = 0; qg < 2; ++qg)
#pragma unroll
        for (int ks = 0; ks < 8; ++ks)
            qh[qg][ks] = *(const bf16x8*)(Qhi + base +
                (size_t)(q0 + qg * 16 + m) * DD + ks * 32 + g * 8);

    // K-frag read coords
    const int r0 = ((m >> 2) << 3) + (m & 3);
    const int f0 = ((m & 3) << 1) ^ (m >> 2);      // fK(r0); fK(r0+4) = f0^4

    // staging coords (2 chunks each of K and V per thread)
    const int kr1 = tid >> 5, kc1 = tid & 31;          // chunks tid, tid+512
    const int kr2 = (tid + 512) >> 5, kc2 = tid & 31;
    const int fK1 = (kr1 & 4) ^ ((kr1 & 3) << 1) ^ ((kr1 >> 3) & 3);
    const int fK2 = (kr2 & 4) ^ ((kr2 & 3) << 1) ^ ((kr2 >> 3) & 3);
    const int kd1 = kr1 * 264 + ((kc1 ^ fK1) << 3);    // LDS u16 index
    const int kd2 = kr2 * 264 + ((kc2 ^ fK2) << 3);
    const int kg1 = kr1 * 256 + (kc1 << 3);            // global u16 offset in tile
    const int kg2 = kr2 * 256 + (kc2 << 3);
    const int vr1 = tid >> 2, vc1 = tid & 3;
    const int vr2 = vr1 + 128, vc2 = vc1;
    const int vd1 = vr1 * 40 + (vc1 << 3);
    const int vd2 = vr2 * 40 + (vc2 << 3);
    const size_t vg1 = (size_t)vr1 * SS + (vc1 << 3);
    const size_t vg2 = (size_t)vr2 * SS + (vc2 << 3);

    float m2[2] = {-1e30f, -1e30f}, l[2] = {0.f, 0.f};
    f32x4 acc[2][16];
#pragma unroll
    for (int qg = 0; qg < 2; ++qg)
#pragma unroll
        for (int e = 0; e < 16; ++e) acc[qg][e] = {0.f, 0.f, 0.f, 0.f};

    bf16x8 rk0, rk1, rv0, rv1;
#define ISSUE_LOADS(kvn)                                                        \
    {   const u16* Kg = Khi + base + (size_t)(kvn) * DD;                        \
        const u16* Vg = Vhi + base + (kvn);                                     \
        rk0 = *(const bf16x8*)(Kg + kg1);                                       \
        rk1 = *(const bf16x8*)(Kg + kg2);                                       \
        rv0 = *(const bf16x8*)(Vg + vg1);                                       \
        rv1 = *(const bf16x8*)(Vg + vg2);  }
#define WRITE_BUF(p)                                                            \
    {   u16* Kb = &lK[p][0][0]; u16* Vb = &lV[p][0][0];                         \
        *(bf16x8*)(Kb + kd1) = rk0; *(bf16x8*)(Kb + kd2) = rk1;                 \
        *(bf16x8*)(Vb + vd1) = rv0; *(bf16x8*)(Vb + vd2) = rv1;  }

    ISSUE_LOADS(0);
    WRITE_BUF(0);
    __syncthreads();

    for (int t = 0; t < 64; ++t) {
        if (t < 63) ISSUE_LOADS((t + 1) * 32);

        const u16* Kb = &lK[t & 1][0][0];
        const u16* Vb = &lV[t & 1][0][0];

        // QK^T: s[qg][t2] -> keys pi_t2(4g+r) for q = q0+qg*16+m
        f32x4 s[2][2];
        s[0][0] = {0.f,0.f,0.f,0.f}; s[0][1] = {0.f,0.f,0.f,0.f};
        s[1][0] = {0.f,0.f,0.f,0.f}; s[1][1] = {0.f,0.f,0.f,0.f};
#pragma unroll
        for (int ks = 0; ks < 8; ++ks) {
            const int c0 = (((ks << 2) | g) ^ f0) << 3;
            bf16x8 k0 = *(const bf16x8*)(Kb + r0 * 264 + c0);
            bf16x8 k1 = *(const bf16x8*)(Kb + (r0 + 4) * 264 + (c0 ^ 32));
            s[0][0] = MFMA(k0, qh[0][ks], s[0][0]);
            s[0][1] = MFMA(k1, qh[0][ks], s[0][1]);
            s[1][0] = MFMA(k0, qh[1][ks], s[1][0]);
            s[1][1] = MFMA(k1, qh[1][ks], s[1][1]);
        }

        // online softmax (log2 domain), per q-group
        bf16x8 pb[2];
#pragma unroll
        for (int qg = 0; qg < 2; ++qg) {
            f32x4 vm;
#pragma unroll
            for (int r = 0; r < 4; ++r) vm[r] = fmaxf(s[qg][0][r], s[qg][1][r]);
            float mx = fmaxf(fmaxf(vm[0], vm[1]), fmaxf(vm[2], vm[3]));
            mx = fmaxf(mx, __shfl_xor(mx, 16));
            mx = fmaxf(mx, __shfl_xor(mx, 32));

            if (__ballot(mx > m2[qg] + 11.0f)) {   // defer-rescale (T13)
                float mn = fmaxf(m2[qg], mx);
                float f = __builtin_amdgcn_exp2f(m2[qg] - mn);
                m2[qg] = mn;
                l[qg] *= f;
#pragma unroll
                for (int e = 0; e < 16; ++e) acc[qg][e] *= f;
            }
#pragma unroll
            for (int t2 = 0; t2 < 2; ++t2)
#pragma unroll
                for (int r = 0; r < 4; ++r)
                    s[qg][t2][r] = __builtin_amdgcn_exp2f(s[qg][t2][r] - m2[qg]);

            f32x4 vs = s[qg][0] + s[qg][1];
            float sum = (vs[0] + vs[1]) + (vs[2] + vs[3]);
            sum += __shfl_xor(sum, 16);
            sum += __shfl_xor(sum, 32);
            l[qg] += sum;

#pragma unroll
            for (int j = 0; j < 4; ++j) pb[qg][j] = (short)f2bf_rtn(s[qg][0][j]);
#pragma unroll
            for (int j = 0; j < 4; ++j) pb[qg][4 + j] = (short)f2bf_rtn(s[qg][1][j]);
        }

        // PV: acc[qg][e16] += V^T-frag * P-frag (V-frag shared across q-groups)
#pragma unroll
        for (int e16 = 0; e16 < 16; ++e16) {
            bf16x8 vf = *(const bf16x8*)(Vb + e16 * 640 + m * 40 + (g << 3));
            acc[0][e16] = MFMA(vf, pb[0], acc[0][e16]);
            acc[1][e16] = MFMA(vf, pb[1], acc[1][e16]);
        }

        if (t < 63) WRITE_BUF((t + 1) & 1);
        __syncthreads();
    }
#undef ISSUE_LOADS
#undef WRITE_BUF

    // epilogue: lane owns q = q0+qg*16+m; e = e16*16 + 4g + r
    const int b = bh >> 3, h = bh & 7;
#pragma unroll
    for (int qg = 0; qg < 2; ++qg) {
        float inv = 1.0f / l[qg];
        const size_t rowbase = ((size_t)(b * SS + q0 + qg * 16 + m)) * (DD * HH) + h;
#pragma unroll
        for (int e16 = 0; e16 < 16; ++e16)
#pragma unroll
            for (int r = 0; r < 4; ++r) {
                int e = e16 * 16 + g * 4 + r;
                float v = acc[qg][e16][r] * inv;
                u16 hh2, ll2; split2(v, hh2, ll2);
                Rhi[rowbase + (size_t)e * HH] = hh2;
                Rlo[rowbase + (size_t)e * HH] = ll2;
            }
    }
}

// ---------------- launcher ----------------
extern "C" void kernel_launch(void* const* d_in, const int* in_sizes, int n_in,
                              void* d_out, int out_size, void* d_ws, size_t ws_size,
                              hipStream_t stream)
{
    (void)in_sizes; (void)n_in; (void)out_size; (void)ws_size;
    const float* k_in = (const float*)d_in[0];
    const float* v_in = (const float*)d_in[1];
    const float* q_in = (const float*)d_in[2];
    const float* Wk   = (const float*)d_in[3];
    const float* bk   = (const float*)d_in[4];
    const float* Wv   = (const float*)d_in[5];
    const float* bv   = (const float*)d_in[6];
    const float* Wq   = (const float*)d_in[7];
    const float* bq   = (const float*)d_in[8];
    const float* Wo   = (const float*)d_in[9];
    const float* bo   = (const float*)d_in[10];
    float* out = (float*)d_out;

    char* p = (char*)d_ws;
    const size_t MB = 1024 * 1024;
    u16* WqH = (u16*)(p + 0 * MB);
    u16* WqL = (u16*)(p + 1 * MB);
    u16* WkH = (u16*)(p + 2 * MB);
    u16* WkL = (u16*)(p + 3 * MB);
    u16* WvH = (u16*)(p + 4 * MB);
    u16* WvL = (u16*)(p + 5 * MB);
    u16* WoH = (u16*)(p + 6 * MB);
    u16* WoL = (u16*)(p + 7 * MB);
    const size_t PB = 32 * MB;
    u16* QH  = (u16*)(p + 8 * MB);
    u16* KH  = (u16*)(p + 8 * MB + 1 * PB);
    u16* VTH = (u16*)(p + 8 * MB + 2 * PB);
    u16* RH  = (u16*)(p + 8 * MB + 3 * PB);
    u16* RL  = (u16*)(p + 8 * MB + 4 * PB);

    prep_w<<<dim3(2048), dim3(256), 0, stream>>>(Wq, WqH, WqL);
    prep_w<<<dim3(2048), dim3(256), 0, stream>>>(Wk, WkH, WkL);
    prep_w<<<dim3(2048), dim3(256), 0, stream>>>(Wv, WvH, WvL);
    prep_wo<<<dim3(256), dim3(256), 0, stream>>>(Wo, WoH, WoL);

    // projections: M=8192, N=2048, K=256.
    // Q scaled by log2(e)/sqrt(D) -> logits directly in log2 domain.
    const float qscale = 1.4426950408889634f / 16.0f;
    gemm_split<0, true, 1, 128><<<dim3(16, 64), dim3(512), 0, stream>>>(
        q_in, nullptr, nullptr, WqH, WqL, bq, QH, nullptr, 8192, 2048, 256, qscale);
    gemm_split<0, true, 1, 128><<<dim3(16, 64), dim3(512), 0, stream>>>(
        k_in, nullptr, nullptr, WkH, WkL, bk, KH, nullptr, 8192, 2048, 256, 1.0f);
    gemm_split<1, true, 2, 128><<<dim3(16, 64), dim3(512), 0, stream>>>(
        v_in, nullptr, nullptr, WvH, WvL, bv, VTH, nullptr, 8192, 2048, 256, 1.0f);

    // flash attention: 8 q-tiles (256 q each) x 32 (b,h) = 256 blocks
    attn_kernel<<<dim3(8, 32), dim3(512), 0, stream>>>(
        QH, KH, VTH, RH, RL);

    // output projection: M=8192, N=256, K=2048; 128x64 tiles -> 256 blocks
    gemm_split<2, false, 3, 64><<<dim3(4, 64), dim3(512), 0, stream>>>(
        nullptr, RH, RL, WoH, WoL, bo, nullptr, out, 8192, 256, 2048, 1.0f);
}

// Round 6
// 480.599 us; speedup vs baseline: 2.7356x; 1.0124x over previous
//
#include <hip/hip_runtime.h>

#define BB 4
#define SS 2048
#define DD 256
#define HH 8

typedef unsigned short u16;
typedef __attribute__((ext_vector_type(8))) short bf16x8;
typedef __attribute__((ext_vector_type(4))) float f32x4;

__device__ __forceinline__ f32x4 MFMA(bf16x8 a, bf16x8 b, f32x4 c) {
    return __builtin_amdgcn_mfma_f32_16x16x32_bf16(a, b, c, 0, 0, 0);
}

__device__ __forceinline__ u16 f2bf_rtn(float x) {
    unsigned u = __float_as_uint(x);
    u += 0x7FFFu + ((u >> 16) & 1u);
    return (u16)(u >> 16);
}
__device__ __forceinline__ float bf2f(u16 h) {
    return __uint_as_float(((unsigned)h) << 16);
}
__device__ __forceinline__ void split2(float x, u16 &hi, u16 &lo) {
    hi = f2bf_rtn(x);
    lo = f2bf_rtn(x - bf2f(hi));
}

// ---------------- weight prep: transpose + hi/lo split ----------------
__global__ void prep_w(const float* __restrict__ W, u16* __restrict__ Whi,
                       u16* __restrict__ Wlo) {
    int n = blockIdx.x;            // 0..2047
    int h = n >> 8, e = n & 255;
    int d = threadIdx.x;           // 0..255
    float x = W[((size_t)h * 256 + d) * 256 + e];
    u16 hi, lo; split2(x, hi, lo);
    Whi[(size_t)n * 256 + d] = hi;
    Wlo[(size_t)n * 256 + d] = lo;
}

__global__ void prep_wo(const float* __restrict__ W, u16* __restrict__ Whi,
                        u16* __restrict__ Wlo) {
    int n = blockIdx.x;            // 0..255
    for (int k = threadIdx.x; k < 2048; k += 256) {
        float x = W[(size_t)k * 256 + n];
        u16 hi, lo; split2(x, hi, lo);
        Whi[(size_t)n * 2048 + k] = hi;
        Wlo[(size_t)n * 2048 + k] = lo;
    }
}

// ---------------- split-bf16 GEMM: C = A * B^T(stored [N][K]) + bias ----------------
template<int MODE, bool AFP32, int TERMS, int BN>
__global__ __launch_bounds__(512, 2) void gemm_split(
    const float* __restrict__ Af,
    const u16* __restrict__ Ahi, const u16* __restrict__ Alo,
    const u16* __restrict__ Bhi, const u16* __restrict__ Blo,
    const float* __restrict__ bias,
    u16* __restrict__ Ohi,
    float* __restrict__ Of,
    int M, int N, int K, float scale)
{
    constexpr int WN = (BN == 128) ? 4 : 2;
    constexpr int WM = 8 / WN;
    constexpr int MSUB = (128 / WM) / 16;
    constexpr int NSUB = (BN / WN) / 16;

    __shared__ u16 lA_hi[128][40], lA_lo[128][40];
    __shared__ u16 lB_hi[128][40], lB_lo[128][40];

    const int tid = threadIdx.x;
    const int lane = tid & 63, wave = tid >> 6;
    const int wm = wave / WN, wn = wave % WN;
    const int m0 = blockIdx.y * 128, n0 = blockIdx.x * BN;

    f32x4 acc[MSUB][NSUB];
#pragma unroll
    for (int i = 0; i < MSUB; ++i)
#pragma unroll
        for (int j = 0; j < NSUB; ++j) acc[i][j] = {0.f, 0.f, 0.f, 0.f};

    const int srow = tid >> 2;
    const int schunk = (tid & 3) * 8;

    for (int k0 = 0; k0 < K; k0 += 32) {
        __syncthreads();
        if (AFP32) {
            const float* g = Af + (size_t)(m0 + srow) * K + k0 + schunk;
            f32x4 a0 = *(const f32x4*)g;
            f32x4 a1 = *(const f32x4*)(g + 4);
            bf16x8 hv;
#pragma unroll
            for (int j = 0; j < 4; ++j) hv[j] = (short)f2bf_rtn(a0[j]);
#pragma unroll
            for (int j = 0; j < 4; ++j) hv[4 + j] = (short)f2bf_rtn(a1[j]);
            *(bf16x8*)&lA_hi[srow][schunk] = hv;
        } else {
            size_t ga = (size_t)(m0 + srow) * K + k0 + schunk;
            *(bf16x8*)&lA_hi[srow][schunk] = *(const bf16x8*)(Ahi + ga);
            if (TERMS == 3)
                *(bf16x8*)&lA_lo[srow][schunk] = *(const bf16x8*)(Alo + ga);
        }
        if (BN == 128 || tid < BN * 4) {
            size_t gb = (size_t)(n0 + srow) * K + k0 + schunk;
            *(bf16x8*)&lB_hi[srow][schunk] = *(const bf16x8*)(Bhi + gb);
            if (TERMS >= 2)
                *(bf16x8*)&lB_lo[srow][schunk] = *(const bf16x8*)(Blo + gb);
        }
        __syncthreads();

        const int kf = (lane >> 4) * 8;
        const int rA = wm * (128 / WM), rB = wn * (BN / WN);
        bf16x8 bh[NSUB], bl[NSUB];
#pragma unroll
        for (int ns = 0; ns < NSUB; ++ns) {
            bh[ns] = *(bf16x8*)&lB_hi[rB + ns * 16 + (lane & 15)][kf];
            if (TERMS >= 2)
                bl[ns] = *(bf16x8*)&lB_lo[rB + ns * 16 + (lane & 15)][kf];
        }
#pragma unroll
        for (int ms = 0; ms < MSUB; ++ms) {
            bf16x8 ah = *(bf16x8*)&lA_hi[rA + ms * 16 + (lane & 15)][kf];
            bf16x8 al;
            if (TERMS == 3) al = *(bf16x8*)&lA_lo[rA + ms * 16 + (lane & 15)][kf];
#pragma unroll
            for (int ns = 0; ns < NSUB; ++ns) {
                acc[ms][ns] = MFMA(ah, bh[ns], acc[ms][ns]);
                if (TERMS == 3) acc[ms][ns] = MFMA(al, bh[ns], acc[ms][ns]);
                if (TERMS >= 2) acc[ms][ns] = MFMA(ah, bl[ns], acc[ms][ns]);
            }
        }
    }

#pragma unroll
    for (int ms = 0; ms < MSUB; ++ms)
#pragma unroll
        for (int ns = 0; ns < NSUB; ++ns)
#pragma unroll
            for (int r = 0; r < 4; ++r) {
                int row = m0 + wm * (128 / WM) + ms * 16 + (lane >> 4) * 4 + r;
                int col = n0 + wn * (BN / WN) + ns * 16 + (lane & 15);
                float v = (acc[ms][ns][r] + bias[col]) * scale;
                if (MODE == 2) {
                    Of[(size_t)row * N + col] = v;
                } else {
                    int b = row >> 11, s = row & 2047, hh = col >> 8, e = col & 255;
                    size_t idx;
                    if (MODE == 0)
                        idx = ((size_t)(b * HH + hh) * SS + s) * DD + e;
                    else
                        idx = ((size_t)(b * HH + hh) * DD + e) * SS + s;
                    Ohi[idx] = f2bf_rtn(v);
                }
            }
}

// ---------------- flash attention: 32q/wave, fixed-m softmax, dbuf pipeline ----------------
// Swapped QK^T; pi(l)=8*(l>>2)+(l&3)+4t covers keys 0..31 for t in {0,1}; exp'd S^T
// registers ARE the PV B-fragments. Fixed softmax reference point m=8 (log2 domain,
// logits bounded |s|<<8): no online max, no rescale, l-reduction deferred to epilogue
// -> zero cross-lane ops and zero branches in the k-loop.
// K LDS [32][264], row r's 16B-slot X stored at X^rho(r), rho(r)=((r>>3)&3)<<1:
// QK read slot = (m&3)+4t+((K4|g)^rho(b)) mod 8 -> exactly 8 lanes/slot (uniform).
// V LDS [256][40] (5-slot rows, gcd(5,8)=1 -> uniform). One barrier per tile.
__global__ __launch_bounds__(512, 2) void attn_kernel(
    const u16* __restrict__ Qhi,
    const u16* __restrict__ Khi,
    const u16* __restrict__ Vhi,
    u16* __restrict__ Rhi, u16* __restrict__ Rlo)
{
    __shared__ u16 lK[2][32][264];
    __shared__ u16 lV[2][256][40];

    const int tid = threadIdx.x, lane = tid & 63, wave = tid >> 6;
    const int m = lane & 15, g = lane >> 4;
    const int bh = blockIdx.y;                     // 0..31 (b*8+h)
    const size_t base = (size_t)bh * SS * DD;
    const int q0 = blockIdx.x * 256 + wave * 32;

    // Q fragments, 2 q-groups of 16 (B-operand: col=q=m, d-chunk g*8 within ks*32)
    bf16x8 qh[2][8];
#pragma unroll
    for (int qg = 0; qg < 2; ++qg)
#pragma unroll
        for (int ks = 0; ks < 8; ++ks)
            qh[qg][ks] = *(const bf16x8*)(Qhi + base +
                (size_t)(q0 + qg * 16 + m) * DD + ks * 32 + g * 8);

    // K-frag read coords: rows r0, r0+4; col slot X = ((ks<<2)|g) ^ rho, rho=(m>>2)<<1
    const int r0 = ((m >> 2) << 3) + (m & 3);
    const int rho = (m >> 2) << 1;

    // staging coords (2 chunks each of K and V per thread)
    const int kr1 = tid >> 5, kc1 = tid & 31;          // K rows 0..15 / 16..31
    const int kr2 = (tid + 512) >> 5, kc2 = tid & 31;
    const int kd1 = kr1 * 264 + ((kc1 ^ (((kr1 >> 3) & 3) << 1)) << 3);
    const int kd2 = kr2 * 264 + ((kc2 ^ (((kr2 >> 3) & 3) << 1)) << 3);
    const int kg1 = kr1 * 256 + (kc1 << 3);            // global u16 offset in tile
    const int kg2 = kr2 * 256 + (kc2 << 3);
    const int vr1 = tid >> 2, vc1 = tid & 3;
    const int vr2 = vr1 + 128, vc2 = vc1;
    const int vd1 = vr1 * 40 + (vc1 << 3);
    const int vd2 = vr2 * 40 + (vc2 << 3);
    const size_t vg1 = (size_t)vr1 * SS + (vc1 << 3);
    const size_t vg2 = (size_t)vr2 * SS + (vc2 << 3);

    f32x4 lsum[2] = {{0.f,0.f,0.f,0.f}, {0.f,0.f,0.f,0.f}};
    f32x4 acc[2][16];
#pragma unroll
    for (int qg = 0; qg < 2; ++qg)
#pragma unroll
        for (int e = 0; e < 16; ++e) acc[qg][e] = {0.f, 0.f, 0.f, 0.f};

    bf16x8 rk0, rk1, rv0, rv1;
#define ISSUE_LOADS(kvn)                                                        \
    {   const u16* Kg = Khi + base + (size_t)(kvn) * DD;                        \
        const u16* Vg = Vhi + base + (kvn);                                     \
        rk0 = *(const bf16x8*)(Kg + kg1);                                       \
        rk1 = *(const bf16x8*)(Kg + kg2);                                       \
        rv0 = *(const bf16x8*)(Vg + vg1);                                       \
        rv1 = *(const bf16x8*)(Vg + vg2);  }
#define WRITE_BUF(p)                                                            \
    {   u16* Kb = &lK[p][0][0]; u16* Vb = &lV[p][0][0];                         \
        *(bf16x8*)(Kb + kd1) = rk0; *(bf16x8*)(Kb + kd2) = rk1;                 \
        *(bf16x8*)(Vb + vd1) = rv0; *(bf16x8*)(Vb + vd2) = rv1;  }

    ISSUE_LOADS(0);
    WRITE_BUF(0);
    __syncthreads();

    for (int t = 0; t < 64; ++t) {
        if (t < 63) ISSUE_LOADS((t + 1) * 32);

        const u16* Kb = &lK[t & 1][0][0];
        const u16* Vb = &lV[t & 1][0][0];

        // QK^T: s[qg][t2] -> keys 8g+r+4*t2 for q = q0+qg*16+m
        f32x4 s[2][2];
        s[0][0] = {0.f,0.f,0.f,0.f}; s[0][1] = {0.f,0.f,0.f,0.f};
        s[1][0] = {0.f,0.f,0.f,0.f}; s[1][1] = {0.f,0.f,0.f,0.f};
        __builtin_amdgcn_s_setprio(1);
#pragma unroll
        for (int ks = 0; ks < 8; ++ks) {
            const int c0 = ((((ks << 2) | g) ^ rho)) << 3;
            bf16x8 k0 = *(const bf16x8*)(Kb + r0 * 264 + c0);
            bf16x8 k1 = *(const bf16x8*)(Kb + (r0 + 4) * 264 + c0);
            s[0][0] = MFMA(k0, qh[0][ks], s[0][0]);
            s[0][1] = MFMA(k1, qh[0][ks], s[0][1]);
            s[1][0] = MFMA(k0, qh[1][ks], s[1][0]);
            s[1][1] = MFMA(k1, qh[1][ks], s[1][1]);
        }
        __builtin_amdgcn_s_setprio(0);

        // fixed-m softmax: P = exp2(s - 8); l deferred (pure lane-local sums)
        bf16x8 pb[2];
#pragma unroll
        for (int qg = 0; qg < 2; ++qg) {
#pragma unroll
            for (int t2 = 0; t2 < 2; ++t2)
#pragma unroll
                for (int r = 0; r < 4; ++r)
                    s[qg][t2][r] = __builtin_amdgcn_exp2f(s[qg][t2][r] - 8.0f);
            lsum[qg] += s[qg][0] + s[qg][1];
#pragma unroll
            for (int j = 0; j < 4; ++j) pb[qg][j] = (short)f2bf_rtn(s[qg][0][j]);
#pragma unroll
            for (int j = 0; j < 4; ++j) pb[qg][4 + j] = (short)f2bf_rtn(s[qg][1][j]);
        }

        // PV: acc[qg][e16] += V^T-frag * P-frag (V-frag shared across q-groups)
        __builtin_amdgcn_s_setprio(1);
#pragma unroll
        for (int e16 = 0; e16 < 16; ++e16) {
            bf16x8 vf = *(const bf16x8*)(Vb + e16 * 640 + m * 40 + (g << 3));
            acc[0][e16] = MFMA(vf, pb[0], acc[0][e16]);
            acc[1][e16] = MFMA(vf, pb[1], acc[1][e16]);
        }
        __builtin_amdgcn_s_setprio(0);

        if (t < 63) WRITE_BUF((t + 1) & 1);
        __syncthreads();
    }
#undef ISSUE_LOADS
#undef WRITE_BUF

    // epilogue: reduce l (components + lanes m+16g), then scale and store
    const int b = bh >> 3, h = bh & 7;
#pragma unroll
    for (int qg = 0; qg < 2; ++qg) {
        float l = (lsum[qg][0] + lsum[qg][1]) + (lsum[qg][2] + lsum[qg][3]);
        l += __shfl_xor(l, 16);
        l += __shfl_xor(l, 32);
        float inv = 1.0f / l;
        const size_t rowbase = ((size_t)(b * SS + q0 + qg * 16 + m)) * (DD * HH) + h;
#pragma unroll
        for (int e16 = 0; e16 < 16; ++e16)
#pragma unroll
            for (int r = 0; r < 4; ++r) {
                int e = e16 * 16 + g * 4 + r;
                float v = acc[qg][e16][r] * inv;
                u16 hh2, ll2; split2(v, hh2, ll2);
                Rhi[rowbase + (size_t)e * HH] = hh2;
                Rlo[rowbase + (size_t)e * HH] = ll2;
            }
    }
}

// ---------------- launcher ----------------
extern "C" void kernel_launch(void* const* d_in, const int* in_sizes, int n_in,
                              void* d_out, int out_size, void* d_ws, size_t ws_size,
                              hipStream_t stream)
{
    (void)in_sizes; (void)n_in; (void)out_size; (void)ws_size;
    const float* k_in = (const float*)d_in[0];
    const float* v_in = (const float*)d_in[1];
    const float* q_in = (const float*)d_in[2];
    const float* Wk   = (const float*)d_in[3];
    const float* bk   = (const float*)d_in[4];
    const float* Wv   = (const float*)d_in[5];
    const float* bv   = (const float*)d_in[6];
    const float* Wq   = (const float*)d_in[7];
    const float* bq   = (const float*)d_in[8];
    const float* Wo   = (const float*)d_in[9];
    const float* bo   = (const float*)d_in[10];
    float* out = (float*)d_out;

    char* p = (char*)d_ws;
    const size_t MB = 1024 * 1024;
    u16* WqH = (u16*)(p + 0 * MB);
    u16* WqL = (u16*)(p + 1 * MB);
    u16* WkH = (u16*)(p + 2 * MB);
    u16* WkL = (u16*)(p + 3 * MB);
    u16* WvH = (u16*)(p + 4 * MB);
    u16* WvL = (u16*)(p + 5 * MB);
    u16* WoH = (u16*)(p + 6 * MB);
    u16* WoL = (u16*)(p + 7 * MB);
    const size_t PB = 32 * MB;
    u16* QH  = (u16*)(p + 8 * MB);
    u16* KH  = (u16*)(p + 8 * MB + 1 * PB);
    u16* VTH = (u16*)(p + 8 * MB + 2 * PB);
    u16* RH  = (u16*)(p + 8 * MB + 3 * PB);
    u16* RL  = (u16*)(p + 8 * MB + 4 * PB);

    prep_w<<<dim3(2048), dim3(256), 0, stream>>>(Wq, WqH, WqL);
    prep_w<<<dim3(2048), dim3(256), 0, stream>>>(Wk, WkH, WkL);
    prep_w<<<dim3(2048), dim3(256), 0, stream>>>(Wv, WvH, WvL);
    prep_wo<<<dim3(256), dim3(256), 0, stream>>>(Wo, WoH, WoL);

    // projections: M=8192, N=2048, K=256.
    // Q scaled by log2(e)/sqrt(D) -> logits directly in log2 domain.
    const float qscale = 1.4426950408889634f / 16.0f;
    gemm_split<0, true, 1, 128><<<dim3(16, 64), dim3(512), 0, stream>>>(
        q_in, nullptr, nullptr, WqH, WqL, bq, QH, nullptr, 8192, 2048, 256, qscale);
    gemm_split<0, true, 1, 128><<<dim3(16, 64), dim3(512), 0, stream>>>(
        k_in, nullptr, nullptr, WkH, WkL, bk, KH, nullptr, 8192, 2048, 256, 1.0f);
    gemm_split<1, true, 2, 128><<<dim3(16, 64), dim3(512), 0, stream>>>(
        v_in, nullptr, nullptr, WvH, WvL, bv, VTH, nullptr, 8192, 2048, 256, 1.0f);

    // flash attention: 8 q-tiles (256 q each) x 32 (b,h) = 256 blocks
    attn_kernel<<<dim3(8, 32), dim3(512), 0, stream>>>(
        QH, KH, VTH, RH, RL);

    // output projection: M=8192, N=256, K=2048; 128x64 tiles -> 256 blocks
    gemm_split<2, false, 3, 64><<<dim3(4, 64), dim3(512), 0, stream>>>(
        nullptr, RH, RL, WoH, WoL, bo, nullptr, out, 8192, 256, 2048, 1.0f);
}